// Round 1
// baseline (424.094 us; speedup 1.0000x reference)
//
#include <hip/hip_runtime.h>
#include <math.h>

#define HIDDEN 512
#define BATCH  16
#define NN     2048

// Kernel 1: d[b,n] = rsqrt( sum_k relu(adj[b,n,k]) + 1 )
// One 256-thread block per row of 2048 floats (2 float4 loads/thread).
__global__ __launch_bounds__(256) void k_rowsum(const float* __restrict__ adj,
                                                float* __restrict__ d) {
    const int row = blockIdx.x;                       // 0 .. B*N-1
    const float4* a4 = (const float4*)(adj + (size_t)row * NN);
    const int t = threadIdx.x;
    float4 v0 = a4[t];
    float4 v1 = a4[t + 256];
    float s = fmaxf(v0.x, 0.f) + fmaxf(v0.y, 0.f) + fmaxf(v0.z, 0.f) + fmaxf(v0.w, 0.f)
            + fmaxf(v1.x, 0.f) + fmaxf(v1.y, 0.f) + fmaxf(v1.z, 0.f) + fmaxf(v1.w, 0.f);
    #pragma unroll
    for (int off = 32; off > 0; off >>= 1) s += __shfl_down(s, off);
    __shared__ float ws[4];
    if ((t & 63) == 0) ws[t >> 6] = s;
    __syncthreads();
    if (t == 0) {
        float tot = ws[0] + ws[1] + ws[2] + ws[3] + 1.0f;   // +1 from identity diag
        d[row] = 1.0f / sqrtf(tot);
    }
}

// Kernel 2: w0[b,m] = d[b,0] * (relu(adj[b,0,m]) + (m==0)) * d[b,m]
__global__ __launch_bounds__(256) void k_w0(const float* __restrict__ adj,
                                            const float* __restrict__ d,
                                            float* __restrict__ w0) {
    const int i = blockIdx.x * 256 + threadIdx.x;     // 0 .. B*N-1
    const int b = i >> 11;                            // / NN
    const int m = i & (NN - 1);
    float a = fmaxf(adj[(size_t)b * NN * NN + m], 0.f);
    if (m == 0) a += 1.0f;
    w0[i] = d[b * NN] * a * d[i];
}

// Kernel 3: y[b,h] = sum_m w0[b,m] * feat[b,h,m]
// One block per (b,h) row; feat row is contiguous (feat is [B,H,N]).
__global__ __launch_bounds__(256) void k_y(const float* __restrict__ feat,
                                           const float* __restrict__ w0,
                                           float* __restrict__ y) {
    const int row = blockIdx.x;                       // 0 .. B*H-1
    const int b = row >> 9;                           // / HIDDEN
    const float4* f4 = (const float4*)(feat + (size_t)row * NN);
    const float4* w4 = (const float4*)(w0 + b * NN);
    const int t = threadIdx.x;
    float4 f0 = f4[t], f1 = f4[t + 256];
    float4 q0 = w4[t], q1 = w4[t + 256];
    float s = f0.x * q0.x + f0.y * q0.y + f0.z * q0.z + f0.w * q0.w
            + f1.x * q1.x + f1.y * q1.y + f1.z * q1.z + f1.w * q1.w;
    #pragma unroll
    for (int off = 32; off > 0; off >>= 1) s += __shfl_down(s, off);
    __shared__ float ws[4];
    if ((t & 63) == 0) ws[t >> 6] = s;
    __syncthreads();
    if (t == 0) y[row] = ws[0] + ws[1] + ws[2] + ws[3];
}

// Kernel 4: out[b,k] = tanh( bias[b,k] + sum_h y[b,h] * W[h,k] )
// One thread per (b,k); y[b,h] is wave-uniform (scalar load), W coalesced over k.
__global__ __launch_bounds__(256) void k_out(const float* __restrict__ W,
                                             const float* __restrict__ bias,
                                             const float* __restrict__ y,
                                             float* __restrict__ out) {
    const int i = blockIdx.x * 256 + threadIdx.x;     // 0 .. B*H-1
    const int b = i >> 9;
    const int k = i & (HIDDEN - 1);
    const float* yb = y + b * HIDDEN;
    float s = bias[i];
    #pragma unroll 8
    for (int h = 0; h < HIDDEN; ++h) s += yb[h] * W[h * HIDDEN + k];
    out[i] = tanhf(s);
}

extern "C" void kernel_launch(void* const* d_in, const int* in_sizes, int n_in,
                              void* d_out, int out_size, void* d_ws, size_t ws_size,
                              hipStream_t stream) {
    const float* feat = (const float*)d_in[0];   // [B, H, N]
    const float* adj  = (const float*)d_in[1];   // [B, N, N]
    const float* W    = (const float*)d_in[2];   // [H, H]
    const float* bias = (const float*)d_in[3];   // [B, H]
    float* out = (float*)d_out;                  // [B, H]

    float* d  = (float*)d_ws;                    // B*N
    float* w0 = d + BATCH * NN;                  // B*N
    float* y  = w0 + BATCH * NN;                 // B*H

    k_rowsum<<<BATCH * NN, 256, 0, stream>>>(adj, d);
    k_w0<<<(BATCH * NN) / 256, 256, 0, stream>>>(adj, d, w0);
    k_y<<<BATCH * HIDDEN, 256, 0, stream>>>(feat, w0, y);
    k_out<<<(BATCH * HIDDEN) / 256, 256, 0, stream>>>(W, bias, y, out);
}